// Round 4
// baseline (4376.373 us; speedup 1.0000x reference)
//
#include <hip/hip_runtime.h>
#include <hip/hip_bf16.h>

#define NN 100000
#define NE 400000
#define NG 1000

static constexpr int GBM = 128;
static constexpr int GBN = 64;
static constexpr int GBK = 16;

// ---------------- bf16 <-> f32 helpers (bit-level, RNE) ----------------
__device__ __forceinline__ float bf2f(unsigned short h) {
    return __uint_as_float((unsigned)h << 16);
}
__device__ __forceinline__ unsigned short f2bf(float f) {
    unsigned u = __float_as_uint(f);
    return (unsigned short)((u + 0x7FFFu + ((u >> 16) & 1u)) >> 16);
}

// ---------------- diagnostic fallback: report ws_size via absmax ----------------
__global__ void diag_kernel(float* __restrict__ out, int n, float val) {
    int i = blockIdx.x * 256 + threadIdx.x;
    if (i < n) out[i] = val;
}

// ---------------- degree / invdeg ----------------
__global__ void deg_kernel(const int* __restrict__ dst, int* __restrict__ deg) {
    int e = blockIdx.x * 256 + threadIdx.x;
    if (e < NE) atomicAdd(&deg[dst[e]], 1);
}

__global__ void invdeg_kernel(const int* __restrict__ deg, float* __restrict__ invdeg) {
    int n = blockIdx.x * 256 + threadIdx.x;
    if (n < NN) invdeg[n] = 1.0f / (float)(deg[n] > 0 ? deg[n] : 1);
}

// ---------------- conv1 node-level first linear (K=5), bf16 out ----------------
// RQ1[n][0:128] = x[n] @ (Wtop - Wbot) ; RQ1[n][128:256] = x[n] @ Wbot
__global__ void conv1_node_kernel(const float* __restrict__ x, const float* __restrict__ W,
                                  unsigned short* __restrict__ RQ) {
    __shared__ float Ws[1280];  // [10][128]
    for (int i = threadIdx.x; i < 1280; i += 256) Ws[i] = W[i];
    __syncthreads();
    int c = threadIdx.x & 127;
    int which = threadIdx.x >> 7;
    for (int n = blockIdx.x; n < NN; n += gridDim.x) {
        float acc = 0.f;
        #pragma unroll
        for (int r = 0; r < 5; r++) {
            float xv = x[n * 5 + r];
            float bot = Ws[(5 + r) * 128 + c];
            float w = which ? bot : (Ws[r * 128 + c] - bot);
            acc = fmaf(xv, w, acc);
        }
        RQ[(size_t)n * 256 + threadIdx.x] = f2bf(acc);
    }
}

// ---------------- build Wprime[K][2C] from W[2K][C] ----------------
__global__ void wprime_kernel(const float* __restrict__ W, float* __restrict__ Wp, int K, int C) {
    int idx = blockIdx.x * 256 + threadIdx.x;
    if (idx >= K * C) return;
    int k = idx / C, c = idx - k * C;
    float top = W[(size_t)k * C + c], bot = W[(size_t)(K + k) * C + c];
    Wp[(size_t)k * 2 * C + c] = top - bot;
    Wp[(size_t)k * 2 * C + C + c] = bot;
}

// ---------------- gather-stats (NO store): v = R[dst]+Q[src]+bias; col stats ----------------
template<int C>
__global__ void gstats_kernel(const unsigned short* __restrict__ RQ, const int* __restrict__ src,
                              const int* __restrict__ dst, const float* __restrict__ bias,
                              float* __restrict__ ssum, float* __restrict__ ssq) {
    constexpr int EPB = 256 / C;
    int c = threadIdx.x % C;
    int sub = threadIdx.x / C;
    float b = bias[c];
    float ls = 0.f, lq = 0.f;
    for (int e = blockIdx.x * EPB + sub; e < NE; e += gridDim.x * EPB) {
        int d = dst[e], s = src[e];
        float v = (bf2f(RQ[(size_t)d * (2 * C) + c]) + bf2f(RQ[(size_t)s * (2 * C) + C + c])) + b;
        ls += v; lq += v * v;
    }
    __shared__ float red[2][256];
    red[0][threadIdx.x] = ls; red[1][threadIdx.x] = lq;
    __syncthreads();
    if (threadIdx.x < C) {
        float s0 = 0.f, q0 = 0.f;
        #pragma unroll
        for (int g = 0; g < EPB; g++) { s0 += red[0][g * C + c]; q0 += red[1][g * C + c]; }
        atomicAdd(&ssum[c], s0);
        atomicAdd(&ssq[c], q0);
    }
}

// ---------------- GraphNorm stats -> per-channel affine ----------------
__global__ void finalize_kernel(const float* __restrict__ ssum, const float* __restrict__ ssq,
                                const float* __restrict__ gn, int C, float invM,
                                float* __restrict__ alpha, float* __restrict__ beta) {
    int c = threadIdx.x;
    if (c >= C) return;
    float g = gn[c], b = gn[C + c], ms = gn[2 * C + c];
    float m = ssum[c] * invM;
    float var = ssq[c] * invM - m * m * ms * (2.f - ms);
    float inv = rsqrtf(var + 1e-5f);
    alpha[c] = g * inv;
    beta[c] = b - g * inv * ms * m;
}

// ---------------- typed A-load for the non-gather GEMM path ----------------
__device__ __forceinline__ void loadA4(const float* p, float v[4]) {
    float4 t = *reinterpret_cast<const float4*>(p);
    v[0] = t.x; v[1] = t.y; v[2] = t.z; v[3] = t.w;
}
__device__ __forceinline__ void loadA4(const unsigned short* p, float v[4]) {
    ushort4 t = *reinterpret_cast<const ushort4*>(p);
    v[0] = bf2f(t.x); v[1] = bf2f(t.y); v[2] = bf2f(t.z); v[3] = bf2f(t.w);
}

// ---------------- tiled GEMM (fp32 compute) ----------------
// GATHER:   A-row e = RQ[dst[e]][0:K] + RQ[src[e]][K:2K] + biasIn
// NORMRELU: a' = relu(alpha[k]*a + beta[k])
// ROWSC:    a' = a * rowscale[r]
// STATS:    epilogue accumulates per-out-channel sum/sumsq of (acc + biasOut)
// STORE:    write C (bf16 if TC==ushort)
// SCAT:     epilogue h = relu(alphaO*o + betaO); atomicAdd(&hsum[gdst[r]*N + col], h)
template<bool GATHER, bool NORMRELU, bool ROWSC, bool STATS, bool STORE, bool SCAT,
         typename TA, typename TC>
__global__ __launch_bounds__(256) void gemm_kernel(
    const TA* __restrict__ A, const int* __restrict__ gsrc, const int* __restrict__ gdst,
    const float* __restrict__ biasIn, const float* __restrict__ W,
    const float* __restrict__ alpha, const float* __restrict__ beta,
    const float* __restrict__ rowscale, const float* __restrict__ biasOut,
    TC* __restrict__ Cmat, int M, int K, int N,
    float* __restrict__ ssum, float* __restrict__ ssq,
    const float* __restrict__ alphaO, const float* __restrict__ betaO,
    float* __restrict__ hsum) {
    __shared__ float As[GBK][GBM + 4];
    __shared__ float Ws[GBK][GBN];
    __shared__ float sAl[256], sBe[256], sBi[256];
    __shared__ float ssb[16][64], sqb[16][64];
    const int t = threadIdx.x;
    if (NORMRELU) {
        for (int i = t; i < K; i += 256) { sAl[i] = alpha[i]; sBe[i] = beta[i]; }
    }
    if (GATHER) {
        for (int i = t; i < K; i += 256) sBi[i] = biasIn[i];
    }
    const int r0 = blockIdx.y * GBM;
    const int n0 = blockIdx.x * GBN;
    const int lar = t >> 2;         // 0..63
    const int lak = (t & 3) << 2;   // 0,4,8,12
    const int lwk = t >> 4;         // 0..15
    const int lwn = (t & 15) << 2;  // 0..60
    const int tr = t >> 4;          // 0..15
    const int tcc = (t & 15) << 2;
    int da = 0, sa = 0, db = 0, sb = 0;
    if (GATHER) {  // M % GBM == 0 for all GATHER uses
        int ra = r0 + lar;
        da = gdst[ra]; sa = gsrc[ra]; db = gdst[ra + 64]; sb = gsrc[ra + 64];
    }
    float rs0 = 1.f, rs1 = 1.f;
    if (ROWSC) {
        int ra = r0 + lar, rb = r0 + lar + 64;
        rs0 = (ra < M) ? rowscale[ra] : 0.f;
        rs1 = (rb < M) ? rowscale[rb] : 0.f;
    }
    float acc[8][4] = {};
    for (int k0 = 0; k0 < K; k0 += GBK) {
        float va[4] = {0.f, 0.f, 0.f, 0.f}, vb[4] = {0.f, 0.f, 0.f, 0.f};
        if (GATHER) {
            ushort4 r4 = *reinterpret_cast<const ushort4*>(&A[(size_t)da * 2 * K + k0 + lak]);
            ushort4 q4 = *reinterpret_cast<const ushort4*>(&A[(size_t)sa * 2 * K + K + k0 + lak]);
            va[0] = bf2f(r4.x) + bf2f(q4.x); va[1] = bf2f(r4.y) + bf2f(q4.y);
            va[2] = bf2f(r4.z) + bf2f(q4.z); va[3] = bf2f(r4.w) + bf2f(q4.w);
            ushort4 r5 = *reinterpret_cast<const ushort4*>(&A[(size_t)db * 2 * K + k0 + lak]);
            ushort4 q5 = *reinterpret_cast<const ushort4*>(&A[(size_t)sb * 2 * K + K + k0 + lak]);
            vb[0] = bf2f(r5.x) + bf2f(q5.x); vb[1] = bf2f(r5.y) + bf2f(q5.y);
            vb[2] = bf2f(r5.z) + bf2f(q5.z); vb[3] = bf2f(r5.w) + bf2f(q5.w);
        } else {
            int ra = r0 + lar;
            if (ra < M) loadA4(&A[(size_t)ra * K + k0 + lak], va);
            int rb = ra + 64;
            if (rb < M) loadA4(&A[(size_t)rb * K + k0 + lak], vb);
        }
        float4 wv = *reinterpret_cast<const float4*>(&W[(size_t)(k0 + lwk) * N + n0 + lwn]);
        __syncthreads();  // protects previous iter's LDS reads AND sAl/sBe/sBi preload
        #pragma unroll
        for (int j = 0; j < 4; j++) {
            float a = va[j], bv = vb[j];
            int kidx = k0 + lak + j;
            if (GATHER) { a += sBi[kidx]; bv += sBi[kidx]; }
            if (NORMRELU) {
                float al = sAl[kidx], be = sBe[kidx];
                a = fmaxf(fmaf(al, a, be), 0.f);
                bv = fmaxf(fmaf(al, bv, be), 0.f);
            }
            if (ROWSC) { a *= rs0; bv *= rs1; }
            As[lak + j][lar] = a;
            As[lak + j][lar + 64] = bv;
        }
        *reinterpret_cast<float4*>(&Ws[lwk][lwn]) = wv;
        __syncthreads();
        #pragma unroll
        for (int kk = 0; kk < GBK; kk++) {
            float4 w4 = *reinterpret_cast<const float4*>(&Ws[kk][tcc]);
            float4 a04 = *reinterpret_cast<const float4*>(&As[kk][tr * 8]);
            float4 a14 = *reinterpret_cast<const float4*>(&As[kk][tr * 8 + 4]);
            float am[8] = {a04.x, a04.y, a04.z, a04.w, a14.x, a14.y, a14.z, a14.w};
            #pragma unroll
            for (int i = 0; i < 8; i++) {
                acc[i][0] = fmaf(am[i], w4.x, acc[i][0]);
                acc[i][1] = fmaf(am[i], w4.y, acc[i][1]);
                acc[i][2] = fmaf(am[i], w4.z, acc[i][2]);
                acc[i][3] = fmaf(am[i], w4.w, acc[i][3]);
            }
        }
    }
    float4 bv4 = make_float4(0, 0, 0, 0);
    if (biasOut != nullptr) bv4 = *reinterpret_cast<const float4*>(&biasOut[n0 + tcc]);
    float bj[4] = {bv4.x, bv4.y, bv4.z, bv4.w};
    float aO[4] = {0.f, 0.f, 0.f, 0.f}, bO[4] = {0.f, 0.f, 0.f, 0.f};
    if (SCAT) {
        float4 a4 = *reinterpret_cast<const float4*>(&alphaO[n0 + tcc]);
        float4 b4 = *reinterpret_cast<const float4*>(&betaO[n0 + tcc]);
        aO[0] = a4.x; aO[1] = a4.y; aO[2] = a4.z; aO[3] = a4.w;
        bO[0] = b4.x; bO[1] = b4.y; bO[2] = b4.z; bO[3] = b4.w;
    }
    float ps[4] = {0.f, 0.f, 0.f, 0.f}, pq[4] = {0.f, 0.f, 0.f, 0.f};
    #pragma unroll
    for (int i = 0; i < 8; i++) {
        int r = r0 + tr * 8 + i;
        if (r < M) {
            float o[4];
            #pragma unroll
            for (int j = 0; j < 4; j++) {
                o[j] = acc[i][j] + bj[j];
                if (STATS) { ps[j] += o[j]; pq[j] += o[j] * o[j]; }
            }
            if (STORE) {
                if (sizeof(TC) == 2) {
                    ushort4 u;
                    u.x = f2bf(o[0]); u.y = f2bf(o[1]); u.z = f2bf(o[2]); u.w = f2bf(o[3]);
                    *reinterpret_cast<ushort4*>((void*)&Cmat[(size_t)r * N + n0 + tcc]) = u;
                } else {
                    *reinterpret_cast<float4*>((void*)&Cmat[(size_t)r * N + n0 + tcc]) =
                        make_float4(o[0], o[1], o[2], o[3]);
                }
            }
            if (SCAT) {
                int d = gdst[r];
                #pragma unroll
                for (int j = 0; j < 4; j++) {
                    float h = fmaxf(fmaf(aO[j], o[j], bO[j]), 0.f);
                    atomicAdd(&hsum[(size_t)d * N + n0 + tcc + j], h);
                }
            }
        }
    }
    if (STATS) {  // M % GBM == 0 guaranteed for STATS instantiations
        #pragma unroll
        for (int j = 0; j < 4; j++) { ssb[tr][tcc + j] = ps[j]; sqb[tr][tcc + j] = pq[j]; }
        __syncthreads();
        if (t < 64) {
            float s = 0.f, q = 0.f;
            #pragma unroll
            for (int g = 0; g < 16; g++) { s += ssb[g][t]; q += sqb[g][t]; }
            atomicAdd(&ssum[n0 + t], s);
            atomicAdd(&ssq[n0 + t], q);
        }
    }
}

// ---------------- norm+relu a materialized bf16 Y, scatter-add (f32) ----------------
template<int C>
__global__ void aggregate_kernel(const unsigned short* __restrict__ Y, const int* __restrict__ dst,
                                 const float* __restrict__ alpha, const float* __restrict__ beta,
                                 float* __restrict__ hsum) {
    constexpr int EPB = 256 / C;
    int c = threadIdx.x % C;
    int sub = threadIdx.x / C;
    float al = alpha[c], be = beta[c];
    for (int e = blockIdx.x * EPB + sub; e < NE; e += gridDim.x * EPB) {
        float v = fmaxf(fmaf(al, bf2f(Y[(size_t)e * C + c]), be), 0.f);
        atomicAdd(&hsum[(size_t)dst[e] * C + c], v);
    }
}

// ---------------- conv3: fused gather+norm+relu+scatter (C=256), no Y buffer ----------------
__global__ void aggregate_fg_kernel(const unsigned short* __restrict__ RQ,
                                    const int* __restrict__ src, const int* __restrict__ dst,
                                    const float* __restrict__ bias, const float* __restrict__ alpha,
                                    const float* __restrict__ beta, float* __restrict__ hsum) {
    int c = threadIdx.x;  // 256
    float b = bias[c], al = alpha[c], be = beta[c];
    for (int e = blockIdx.x; e < NE; e += gridDim.x) {
        int d = dst[e], s = src[e];
        float v = (bf2f(RQ[(size_t)d * 512 + c]) + bf2f(RQ[(size_t)s * 512 + 256 + c])) + b;
        float h = fmaxf(fmaf(al, v, be), 0.f);
        atomicAdd(&hsum[(size_t)d * 256 + c], h);
    }
}

// ---------------- graph mean pool ----------------
__global__ void pool_kernel(const float* __restrict__ h3sum, const float* __restrict__ invdeg,
                            const int* __restrict__ batch, float* __restrict__ gsum,
                            int* __restrict__ gcnt) {
    int c = threadIdx.x;  // 256
    for (int n = blockIdx.x; n < NN; n += gridDim.x) {
        float v = h3sum[(size_t)n * 256 + c] * invdeg[n];
        int g = batch[n];
        atomicAdd(&gsum[(size_t)g * 256 + c], v);
        if (c == 0) atomicAdd(&gcnt[g], 1);
    }
}

// ---------------- final graph MLP ----------------
__global__ void mlp_kernel(const float* __restrict__ gsum, const int* __restrict__ gcnt,
                           const float* __restrict__ W1, const float* __restrict__ b1,
                           const float* __restrict__ W2, const float* __restrict__ b2,
                           float* __restrict__ out) {
    int g = blockIdx.x;
    int t = threadIdx.x;  // 256
    __shared__ float grow[256];
    __shared__ float r0s[256], r1s[256];
    int cnt = gcnt[g];
    float inv = 1.0f / (float)(cnt > 0 ? cnt : 1);
    grow[t] = gsum[(size_t)g * 256 + t] * inv;
    __syncthreads();
    float acc = b1[t];
    for (int k = 0; k < 256; k++) acc = fmaf(grow[k], W1[k * 256 + t], acc);
    float h = fmaxf(acc, 0.f);
    r0s[t] = h * W2[t * 2 + 0];
    r1s[t] = h * W2[t * 2 + 1];
    __syncthreads();
    for (int s = 128; s > 0; s >>= 1) {
        if (t < s) { r0s[t] += r0s[t + s]; r1s[t] += r1s[t + s]; }
        __syncthreads();
    }
    if (t == 0) {
        out[g * 2 + 0] = r0s[0] + b2[0];
        out[g * 2 + 1] = r1s[0] + b2[1];
    }
}

extern "C" void kernel_launch(void* const* d_in, const int* in_sizes, int n_in,
                              void* d_out, int out_size, void* d_ws, size_t ws_size,
                              hipStream_t stream) {
    const float* x      = (const float*)d_in[0];
    const int*   ei     = (const int*)d_in[1];
    const int*   src    = ei;
    const int*   dstp   = ei + NE;
    const int*   batch  = (const int*)d_in[2];
    const float* c1_w1  = (const float*)d_in[3];
    const float* c1_b1  = (const float*)d_in[4];
    const float* c1_gn1 = (const float*)d_in[5];
    const float* c1_w2  = (const float*)d_in[6];
    const float* c1_b2  = (const float*)d_in[7];
    const float* c1_gn2 = (const float*)d_in[8];
    const float* c1_w3  = (const float*)d_in[9];
    const float* c1_b3  = (const float*)d_in[10];
    const float* c1_gn3 = (const float*)d_in[11];
    const float* c2_w1  = (const float*)d_in[12];
    const float* c2_b1  = (const float*)d_in[13];
    const float* c2_gn1 = (const float*)d_in[14];
    const float* c2_w2  = (const float*)d_in[15];
    const float* c2_b2  = (const float*)d_in[16];
    const float* c2_gn2 = (const float*)d_in[17];
    const float* c3_w1  = (const float*)d_in[18];
    const float* c3_b1  = (const float*)d_in[19];
    const float* c3_gn1 = (const float*)d_in[20];
    const float* lin_w1 = (const float*)d_in[21];
    const float* lin_b1 = (const float*)d_in[22];
    const float* lin_w2 = (const float*)d_in[23];
    const float* lin_b2 = (const float*)d_in[24];
    float* out = (float*)d_out;

    // ======== workspace: ping-pong regions RA / RB (102.4 MB each) + tail (~2.4 MB) ========
    // ws_size is 256 MiB (round-3 diagnostic). Peak live = 204.8 + 2.4 MB. Lifetimes
    // alternate strictly (each step reads one region, writes the other; stream-ordered):
    //   RA: RQ1[NN,256]bf16 -> Y1c[NE,128]bf16 -> RQ2[NN,512]bf16 -> RQ3[NN,512]bf16
    //   RB: Y1b[NE,128]bf16 -> h1sum[NN,128]f32 -> h2sum[NN,256]f32 -> h3sum[NN,256]f32
    // conv2-L2 edge tensor is NEVER materialized: stats pass + recompute-scatter pass.
    constexpr size_t REG_BYTES = (size_t)NE * 128 * 2;  // 102,400,000 (== NN*512*2)
    constexpr size_t NEED = 2 * REG_BYTES + 4 * 1024 * 1024;

    if (ws_size < NEED) {
        diag_kernel<<<(out_size + 255) / 256, 256, 0, stream>>>(
            out, out_size, (float)(ws_size >> 20));
        return;
    }

    char* base = (char*)d_ws;
    unsigned short* RA = (unsigned short*)base;
    unsigned short* RB = (unsigned short*)(base + REG_BYTES);
    float* h1sum = (float*)RB;
    float* h2sum = (float*)RB;
    float* h3sum = (float*)RB;
    char* p = base + 2 * REG_BYTES;
    auto alloc = [&](size_t bytes) -> void* {
        void* r = (void*)p;
        p += (bytes + 255) & ~(size_t)255;
        return r;
    };
    float* Wp     = (float*)alloc((size_t)256 * 512 * 4);
    int*   deg    = (int*)alloc((size_t)NN * 4);
    float* invdeg = (float*)alloc((size_t)NN * 4);
    float* ssum   = (float*)alloc(256 * 4);
    float* ssq    = (float*)alloc(256 * 4);
    float* al0    = (float*)alloc(256 * 4);
    float* be0    = (float*)alloc(256 * 4);
    float* al1    = (float*)alloc(256 * 4);
    float* be1    = (float*)alloc(256 * 4);
    float* gsum   = (float*)alloc((size_t)NG * 256 * 4);
    int*   gcnt   = (int*)alloc((size_t)NG * 4);

    const float invE = 1.0f / (float)NE;
    const unsigned short* NUS = nullptr;

    hipMemsetAsync(deg, 0, (size_t)NN * 4, stream);
    hipMemsetAsync(gsum, 0, (size_t)NG * 256 * 4, stream);
    hipMemsetAsync(gcnt, 0, (size_t)NG * 4, stream);

    deg_kernel<<<(NE + 255) / 256, 256, 0, stream>>>(dstp, deg);
    invdeg_kernel<<<(NN + 255) / 256, 256, 0, stream>>>(deg, invdeg);

    // ================= conv1 =================
    conv1_node_kernel<<<2048, 256, 0, stream>>>(x, c1_w1, RA);  // RQ1 -> RA
    hipMemsetAsync(ssum, 0, 256 * 4, stream);
    hipMemsetAsync(ssq, 0, 256 * 4, stream);
    gstats_kernel<128><<<2048, 256, 0, stream>>>(RA, src, dstp, c1_b1, ssum, ssq);
    finalize_kernel<<<1, 256, 0, stream>>>(ssum, ssq, c1_gn1, 128, invE, al0, be0);

    hipMemsetAsync(ssum, 0, 256 * 4, stream);
    hipMemsetAsync(ssq, 0, 256 * 4, stream);
    {   // L2: Y1b(RB) = relu(norm(gather(RQ1@RA))) @ c1_w2 + b2, +stats   [RQ1 dead after]
        dim3 grid(128 / GBN, NE / GBM);
        gemm_kernel<true, true, false, true, true, false, unsigned short, unsigned short>
            <<<grid, 256, 0, stream>>>(RA, src, dstp, c1_b1, c1_w2, al0, be0, nullptr, c1_b2,
                                       RB, NE, 128, 128, ssum, ssq, nullptr, nullptr, nullptr);
    }
    finalize_kernel<<<1, 256, 0, stream>>>(ssum, ssq, c1_gn2, 128, invE, al0, be0);

    hipMemsetAsync(ssum, 0, 256 * 4, stream);
    hipMemsetAsync(ssq, 0, 256 * 4, stream);
    {   // L3: Y1c(RA) = relu(norm(Y1b@RB)) @ c1_w3 + b3, +stats   [Y1b dead after]
        dim3 grid(128 / GBN, NE / GBM);
        gemm_kernel<false, true, false, true, true, false, unsigned short, unsigned short>
            <<<grid, 256, 0, stream>>>(RB, nullptr, nullptr, nullptr, c1_w3, al0, be0, nullptr,
                                       c1_b3, RA, NE, 128, 128, ssum, ssq, nullptr, nullptr,
                                       nullptr);
    }
    finalize_kernel<<<1, 256, 0, stream>>>(ssum, ssq, c1_gn3, 128, invE, al0, be0);

    hipMemsetAsync(h1sum, 0, (size_t)NN * 128 * 4, stream);  // RB; Y1b dead
    aggregate_kernel<128><<<2048, 256, 0, stream>>>(RA, dstp, al0, be0, h1sum);

    // ================= conv2 =================
    wprime_kernel<<<(128 * 256 + 255) / 256, 256, 0, stream>>>(c2_w1, Wp, 128, 256);
    {   // node GEMM: RQ2(RA) = (h1sum@RB * invdeg) @ Wp   [Y1c dead after aggregate1]
        dim3 grid(512 / GBN, (NN + GBM - 1) / GBM);
        gemm_kernel<false, false, true, false, true, false, float, unsigned short>
            <<<grid, 256, 0, stream>>>(h1sum, nullptr, nullptr, nullptr, Wp, nullptr, nullptr,
                                       invdeg, nullptr, RA, NN, 128, 512, nullptr, nullptr,
                                       nullptr, nullptr, nullptr);
    }
    hipMemsetAsync(ssum, 0, 256 * 4, stream);
    hipMemsetAsync(ssq, 0, 256 * 4, stream);
    gstats_kernel<256><<<2048, 256, 0, stream>>>(RA, src, dstp, c2_b1, ssum, ssq);
    finalize_kernel<<<1, 256, 0, stream>>>(ssum, ssq, c2_gn1, 256, invE, al0, be0);

    hipMemsetAsync(ssum, 0, 256 * 4, stream);
    hipMemsetAsync(ssq, 0, 256 * 4, stream);
    {   // L2 pass A (stats only, no store): stats of relu(norm(gather(RQ2))) @ c2_w2 + b2
        dim3 grid(256 / GBN, NE / GBM);
        gemm_kernel<true, true, false, true, false, false, unsigned short, unsigned short>
            <<<grid, 256, 0, stream>>>(RA, src, dstp, c2_b1, c2_w2, al0, be0, nullptr, c2_b2,
                                       (unsigned short*)nullptr, NE, 256, 256, ssum, ssq,
                                       nullptr, nullptr, nullptr);
    }
    finalize_kernel<<<1, 256, 0, stream>>>(ssum, ssq, c2_gn2, 256, invE, al1, be1);

    hipMemsetAsync(h2sum, 0, (size_t)NN * 256 * 4, stream);  // RB; h1sum dead after node GEMM
    {   // L2 pass B (recompute + fused norm/relu/scatter): h2sum += relu(al1*Y2b+be1) at dst
        dim3 grid(256 / GBN, NE / GBM);
        gemm_kernel<true, true, false, false, false, true, unsigned short, unsigned short>
            <<<grid, 256, 0, stream>>>(RA, src, dstp, c2_b1, c2_w2, al0, be0, nullptr, c2_b2,
                                       (unsigned short*)nullptr, NE, 256, 256, nullptr, nullptr,
                                       al1, be1, h2sum);
    }

    // ================= conv3 =================
    wprime_kernel<<<(256 * 256 + 255) / 256, 256, 0, stream>>>(c3_w1, Wp, 256, 256);
    {   // node GEMM: RQ3(RA) = (h2sum@RB * invdeg) @ Wp   [RQ2 dead after pass B]
        dim3 grid(512 / GBN, (NN + GBM - 1) / GBM);
        gemm_kernel<false, false, true, false, true, false, float, unsigned short>
            <<<grid, 256, 0, stream>>>(h2sum, nullptr, nullptr, nullptr, Wp, nullptr, nullptr,
                                       invdeg, nullptr, RA, NN, 256, 512, nullptr, nullptr,
                                       nullptr, nullptr, nullptr);
    }
    hipMemsetAsync(ssum, 0, 256 * 4, stream);
    hipMemsetAsync(ssq, 0, 256 * 4, stream);
    gstats_kernel<256><<<2048, 256, 0, stream>>>(RA, src, dstp, c3_b1, ssum, ssq);
    finalize_kernel<<<1, 256, 0, stream>>>(ssum, ssq, c3_gn1, 256, invE, al0, be0);

    hipMemsetAsync(h3sum, 0, (size_t)NN * 256 * 4, stream);  // RB; h2sum dead after node GEMM
    aggregate_fg_kernel<<<2048, 256, 0, stream>>>(RA, src, dstp, c3_b1, al0, be0, h3sum);

    // ================= pool + MLP =================
    pool_kernel<<<2048, 256, 0, stream>>>(h3sum, invdeg, batch, gsum, gcnt);
    mlp_kernel<<<NG, 256, 0, stream>>>(gsum, gcnt, lin_w1, lin_b1, lin_w2, lin_b2, out);
}

// Round 5
// 2476.519 us; speedup vs baseline: 1.7671x; 1.7671x over previous
//
#include <hip/hip_runtime.h>
#include <hip/hip_bf16.h>

#define NN 100000
#define NE 400000
#define NG 1000

typedef __attribute__((ext_vector_type(8))) short bf16x8;
typedef __attribute__((ext_vector_type(4))) float f32x4;

// ---------------- bf16 <-> f32 helpers (bit-level, RNE) ----------------
__device__ __forceinline__ float bf2f(unsigned short h) {
    return __uint_as_float((unsigned)h << 16);
}
__device__ __forceinline__ unsigned short f2bf(float f) {
    unsigned u = __float_as_uint(f);
    return (unsigned short)((u + 0x7FFFu + ((u >> 16) & 1u)) >> 16);
}

// ---------------- diagnostic fallback: report ws_size via absmax ----------------
__global__ void diag_kernel(float* __restrict__ out, int n, float val) {
    int i = blockIdx.x * 256 + threadIdx.x;
    if (i < n) out[i] = val;
}

// ---------------- degree / invdeg ----------------
__global__ void deg_kernel(const int* __restrict__ dst, int* __restrict__ deg) {
    int e = blockIdx.x * 256 + threadIdx.x;
    if (e < NE) atomicAdd(&deg[dst[e]], 1);
}

__global__ void invdeg_kernel(const int* __restrict__ deg, float* __restrict__ invdeg) {
    int n = blockIdx.x * 256 + threadIdx.x;
    if (n < NN) invdeg[n] = 1.0f / (float)(deg[n] > 0 ? deg[n] : 1);
}

// ---------------- conv1 node-level first linear (K=5), bf16 out ----------------
__global__ void conv1_node_kernel(const float* __restrict__ x, const float* __restrict__ W,
                                  unsigned short* __restrict__ RQ) {
    __shared__ float Ws[1280];  // [10][128]
    for (int i = threadIdx.x; i < 1280; i += 256) Ws[i] = W[i];
    __syncthreads();
    int c = threadIdx.x & 127;
    int which = threadIdx.x >> 7;
    for (int n = blockIdx.x; n < NN; n += gridDim.x) {
        float acc = 0.f;
        #pragma unroll
        for (int r = 0; r < 5; r++) {
            float xv = x[n * 5 + r];
            float bot = Ws[(5 + r) * 128 + c];
            float w = which ? bot : (Ws[r * 128 + c] - bot);
            acc = fmaf(xv, w, acc);
        }
        RQ[(size_t)n * 256 + threadIdx.x] = f2bf(acc);
    }
}

// ---------------- weight transpose+convert: Wt[N][K] bf16 from W[K][N] f32 ----------------
__global__ void wtrans_kernel(const float* __restrict__ W, unsigned short* __restrict__ Wt,
                              int K, int N) {
    int idx = blockIdx.x * 256 + threadIdx.x;
    if (idx >= K * N) return;
    int c = idx / K, k = idx - c * K;
    Wt[(size_t)c * K + k] = f2bf(W[(size_t)k * N + c]);
}

// ---------------- wprime transposed bf16: Wpt[2C][K] from W[2K][C] ----------------
// Wpt[n][k] = W[k][n]-W[K+k][n] (n<C) ; = W[K+k][n-C] (n>=C)
__global__ void wprime_t_kernel(const float* __restrict__ W, unsigned short* __restrict__ Wpt,
                                int K, int C) {
    int idx = blockIdx.x * 256 + threadIdx.x;
    if (idx >= 2 * C * K) return;
    int n = idx / K, k = idx - n * K;
    float v;
    if (n < C) v = W[(size_t)k * C + n] - W[(size_t)(K + k) * C + n];
    else       v = W[(size_t)(K + k) * C + (n - C)];
    Wpt[(size_t)n * K + k] = f2bf(v);
}

// ---------------- gather-stats (NO store): v = R[dst]+Q[src]+bias; col stats ----------------
template<int C>
__global__ void gstats_kernel(const unsigned short* __restrict__ RQ, const int* __restrict__ src,
                              const int* __restrict__ dst, const float* __restrict__ bias,
                              float* __restrict__ ssum, float* __restrict__ ssq) {
    constexpr int EPB = 256 / C;
    int c = threadIdx.x % C;
    int sub = threadIdx.x / C;
    float b = bias[c];
    float ls = 0.f, lq = 0.f;
    for (int e = blockIdx.x * EPB + sub; e < NE; e += gridDim.x * EPB) {
        int d = dst[e], s = src[e];
        float v = (bf2f(RQ[(size_t)d * (2 * C) + c]) + bf2f(RQ[(size_t)s * (2 * C) + C + c])) + b;
        ls += v; lq += v * v;
    }
    __shared__ float red[2][256];
    red[0][threadIdx.x] = ls; red[1][threadIdx.x] = lq;
    __syncthreads();
    if (threadIdx.x < C) {
        float s0 = 0.f, q0 = 0.f;
        #pragma unroll
        for (int g = 0; g < EPB; g++) { s0 += red[0][g * C + c]; q0 += red[1][g * C + c]; }
        atomicAdd(&ssum[c], s0);
        atomicAdd(&ssq[c], q0);
    }
}

// ---------------- GraphNorm stats -> per-channel affine ----------------
__global__ void finalize_kernel(const float* __restrict__ ssum, const float* __restrict__ ssq,
                                const float* __restrict__ gn, int C, float invM,
                                float* __restrict__ alpha, float* __restrict__ beta) {
    int c = threadIdx.x;
    if (c >= C) return;
    float g = gn[c], b = gn[C + c], ms = gn[2 * C + c];
    float m = ssum[c] * invM;
    float var = ssq[c] * invM - m * m * ms * (2.f - ms);
    float inv = rsqrtf(var + 1e-5f);
    alpha[c] = g * inv;
    beta[c] = b - g * inv * ms * m;
}

// ================= MFMA GEMM: C = act(A) @ Wt^T (+bias), fused epilogues =================
// Block: 256 thr (4 waves), tile 64 x BN, BK=32, K%32==0, N%BN==0.
// GATHER:   A-row e = RQ[dst[e]][0:K] + RQ[src[e]][K:2K] + biasIn   (bf16 RQ, M=NE)
// NORMRELU: a' = relu(alpha[k]*a + beta[k])
// ROWSC:    a' = a * rowscale[row]          (AF32: A is f32)
// STATS:    per-out-channel sum/sumsq of (acc + biasOut) -> atomicAdd ssum/ssq [M%64==0]
// STORE:    Cmat bf16 [M][N] (row-guarded)
// SCAT:     h = relu(alphaO*o + betaO); atomicAdd(&hsum[dst[row]*N + col], h) [M%64==0]
// Fragment mapping (m89/m97-verified): A row=lane&15, k=(lane>>4)*8+j (contig b128);
// B col=lane&15, k contig (staged transposed); D col=lane&15, row=(lane>>4)*4+reg.
template<int BN, bool GATHER, bool NORMRELU, bool ROWSC, bool STATS, bool STORE, bool SCAT,
         bool AF32>
__global__ __launch_bounds__(256) void mgemm_kernel(
    const void* __restrict__ Av, const int* __restrict__ gsrc, const int* __restrict__ gdst,
    const float* __restrict__ biasIn, const unsigned short* __restrict__ Wt,
    const float* __restrict__ alpha, const float* __restrict__ beta,
    const float* __restrict__ rowscale, const float* __restrict__ biasOut,
    unsigned short* __restrict__ Cmat, int M, int K, int N,
    float* __restrict__ ssum, float* __restrict__ ssq,
    const float* __restrict__ alphaO, const float* __restrict__ betaO,
    float* __restrict__ hsum) {
    constexpr int WNC = BN / 4;   // cols per wave
    constexpr int NF = WNC / 16;  // col fragments per wave
    __shared__ __align__(16) unsigned short At[64][40];
    __shared__ __align__(16) unsigned short Bt[BN][40];
    __shared__ float sS[BN], sQ[BN];
    const int t = threadIdx.x;
    const int wave = t >> 6, lane = t & 63;
    const int l15 = lane & 15, lq = lane >> 4;
    const int r0 = blockIdx.y * 64;
    const int n0 = blockIdx.x * BN;
    const int srow = t >> 2, skq = t & 3;  // staging: 4 threads per row, 8 ch each

    if (STATS && t < BN) { sS[t] = 0.f; sQ[t] = 0.f; }

    const int ar = r0 + srow;
    int gd = 0, gs = 0;
    if (GATHER) { gd = gdst[ar]; gs = gsrc[ar]; }
    float rs = 1.f;
    if (ROWSC) rs = (ar < M) ? rowscale[ar] : 0.f;

    const unsigned short* Abf = (const unsigned short*)Av;
    const float* Af = (const float*)Av;

    f32x4 acc[4][NF];
    #pragma unroll
    for (int i = 0; i < 4; i++)
        #pragma unroll
        for (int j = 0; j < NF; j++) acc[i][j] = {0.f, 0.f, 0.f, 0.f};

    for (int k0 = 0; k0 < K; k0 += 32) {
        const int kb = k0 + skq * 8;
        float v[8];
        if (GATHER) {
            ushort4 p0 = *(const ushort4*)&Abf[(size_t)gd * 2 * K + kb];
            ushort4 p1 = *(const ushort4*)&Abf[(size_t)gd * 2 * K + kb + 4];
            ushort4 q0 = *(const ushort4*)&Abf[(size_t)gs * 2 * K + K + kb];
            ushort4 q1 = *(const ushort4*)&Abf[(size_t)gs * 2 * K + K + kb + 4];
            float4 b0 = *(const float4*)&biasIn[kb];
            float4 b1 = *(const float4*)&biasIn[kb + 4];
            v[0] = bf2f(p0.x) + bf2f(q0.x) + b0.x; v[1] = bf2f(p0.y) + bf2f(q0.y) + b0.y;
            v[2] = bf2f(p0.z) + bf2f(q0.z) + b0.z; v[3] = bf2f(p0.w) + bf2f(q0.w) + b0.w;
            v[4] = bf2f(p1.x) + bf2f(q1.x) + b1.x; v[5] = bf2f(p1.y) + bf2f(q1.y) + b1.y;
            v[6] = bf2f(p1.z) + bf2f(q1.z) + b1.z; v[7] = bf2f(p1.w) + bf2f(q1.w) + b1.w;
        } else if (AF32) {
            if (ar < M) {
                float4 f0 = *(const float4*)&Af[(size_t)ar * K + kb];
                float4 f1 = *(const float4*)&Af[(size_t)ar * K + kb + 4];
                v[0] = f0.x; v[1] = f0.y; v[2] = f0.z; v[3] = f0.w;
                v[4] = f1.x; v[5] = f1.y; v[6] = f1.z; v[7] = f1.w;
            } else {
                #pragma unroll
                for (int i = 0; i < 8; i++) v[i] = 0.f;
            }
        } else {
            if (ar < M) {
                ushort4 p0 = *(const ushort4*)&Abf[(size_t)ar * K + kb];
                ushort4 p1 = *(const ushort4*)&Abf[(size_t)ar * K + kb + 4];
                v[0] = bf2f(p0.x); v[1] = bf2f(p0.y); v[2] = bf2f(p0.z); v[3] = bf2f(p0.w);
                v[4] = bf2f(p1.x); v[5] = bf2f(p1.y); v[6] = bf2f(p1.z); v[7] = bf2f(p1.w);
            } else {
                #pragma unroll
                for (int i = 0; i < 8; i++) v[i] = 0.f;
            }
        }
        if (NORMRELU) {
            float4 a0 = *(const float4*)&alpha[kb];
            float4 a1 = *(const float4*)&alpha[kb + 4];
            float4 e0 = *(const float4*)&beta[kb];
            float4 e1 = *(const float4*)&beta[kb + 4];
            float al[8] = {a0.x, a0.y, a0.z, a0.w, a1.x, a1.y, a1.z, a1.w};
            float be[8] = {e0.x, e0.y, e0.z, e0.w, e1.x, e1.y, e1.z, e1.w};
            #pragma unroll
            for (int i = 0; i < 8; i++) v[i] = fmaxf(fmaf(al[i], v[i], be[i]), 0.f);
        }
        if (ROWSC) {
            #pragma unroll
            for (int i = 0; i < 8; i++) v[i] *= rs;
        }
        uint pk[4];
        #pragma unroll
        for (int i = 0; i < 4; i++)
            pk[i] = (uint)f2bf(v[2 * i]) | ((uint)f2bf(v[2 * i + 1]) << 16);
        *(uint4*)&At[srow][skq * 8] = make_uint4(pk[0], pk[1], pk[2], pk[3]);

        // B stage: Wt rows (cols of W) are contiguous in k
        for (int i = t; i < BN * 4; i += 256) {
            int col = i >> 2, kq = i & 3;
            *(uint4*)&Bt[col][kq * 8] =
                *(const uint4*)&Wt[(size_t)(n0 + col) * K + k0 + kq * 8];
        }
        __syncthreads();
        bf16x8 af[4];
        #pragma unroll
        for (int rf = 0; rf < 4; rf++)
            af[rf] = *(const bf16x8*)&At[16 * rf + l15][lq * 8];
        bf16x8 bfr[NF];
        #pragma unroll
        for (int cf = 0; cf < NF; cf++)
            bfr[cf] = *(const bf16x8*)&Bt[wave * WNC + 16 * cf + l15][lq * 8];
        #pragma unroll
        for (int rf = 0; rf < 4; rf++)
            #pragma unroll
            for (int cf = 0; cf < NF; cf++)
                acc[rf][cf] = __builtin_amdgcn_mfma_f32_16x16x32_bf16(
                    af[rf], bfr[cf], acc[rf][cf], 0, 0, 0);
        __syncthreads();
    }

    // ---------------- epilogue ----------------
    int cA[NF];
    float bO[NF], aO[NF], bOo[NF];
    #pragma unroll
    for (int cf = 0; cf < NF; cf++) {
        cA[cf] = n0 + wave * WNC + 16 * cf + l15;
        bO[cf] = (biasOut != nullptr) ? biasOut[cA[cf]] : 0.f;
        if (SCAT) { aO[cf] = alphaO[cA[cf]]; bOo[cf] = betaO[cA[cf]]; }
    }
    float ps[NF], pq[NF];
    #pragma unroll
    for (int cf = 0; cf < NF; cf++) { ps[cf] = 0.f; pq[cf] = 0.f; }
    #pragma unroll
    for (int rf = 0; rf < 4; rf++) {
        int rb = r0 + 16 * rf + lq * 4;
        int dd[4];
        if (SCAT) {
            #pragma unroll
            for (int jj = 0; jj < 4; jj++) dd[jj] = gdst[rb + jj];
        }
        #pragma unroll
        for (int cf = 0; cf < NF; cf++) {
            #pragma unroll
            for (int jj = 0; jj < 4; jj++) {
                float o = acc[rf][cf][jj] + bO[cf];
                if (STATS) { ps[cf] += o; pq[cf] += o * o; }
                if (STORE) {
                    int r = rb + jj;
                    if (r < M) Cmat[(size_t)r * N + cA[cf]] = f2bf(o);
                }
                if (SCAT) {
                    float h = fmaxf(fmaf(aO[cf], o, bOo[cf]), 0.f);
                    atomicAdd(&hsum[(size_t)dd[jj] * N + cA[cf]], h);
                }
            }
        }
    }
    if (STATS) {
        #pragma unroll
        for (int cf = 0; cf < NF; cf++) {
            float s = ps[cf], q = pq[cf];
            s += __shfl_xor(s, 16); s += __shfl_xor(s, 32);
            q += __shfl_xor(q, 16); q += __shfl_xor(q, 32);
            if (lq == 0) {
                atomicAdd(&sS[cA[cf] - n0], s);
                atomicAdd(&sQ[cA[cf] - n0], q);
            }
        }
        __syncthreads();
        if (t < BN) {
            atomicAdd(&ssum[n0 + t], sS[t]);
            atomicAdd(&ssq[n0 + t], sQ[t]);
        }
    }
}

// ---------------- norm+relu a materialized bf16 Y, scatter-add (f32) ----------------
template<int C>
__global__ void aggregate_kernel(const unsigned short* __restrict__ Y, const int* __restrict__ dst,
                                 const float* __restrict__ alpha, const float* __restrict__ beta,
                                 float* __restrict__ hsum) {
    constexpr int EPB = 256 / C;
    int c = threadIdx.x % C;
    int sub = threadIdx.x / C;
    float al = alpha[c], be = beta[c];
    for (int e = blockIdx.x * EPB + sub; e < NE; e += gridDim.x * EPB) {
        float v = fmaxf(fmaf(al, bf2f(Y[(size_t)e * C + c]), be), 0.f);
        atomicAdd(&hsum[(size_t)dst[e] * C + c], v);
    }
}

// ---------------- conv3: fused gather+norm+relu+scatter (C=256), no Y buffer ----------------
__global__ void aggregate_fg_kernel(const unsigned short* __restrict__ RQ,
                                    const int* __restrict__ src, const int* __restrict__ dst,
                                    const float* __restrict__ bias, const float* __restrict__ alpha,
                                    const float* __restrict__ beta, float* __restrict__ hsum) {
    int c = threadIdx.x;  // 256
    float b = bias[c], al = alpha[c], be = beta[c];
    for (int e = blockIdx.x; e < NE; e += gridDim.x) {
        int d = dst[e], s = src[e];
        float v = (bf2f(RQ[(size_t)d * 512 + c]) + bf2f(RQ[(size_t)s * 512 + 256 + c])) + b;
        float h = fmaxf(fmaf(al, v, be), 0.f);
        atomicAdd(&hsum[(size_t)d * 256 + c], h);
    }
}

// ---------------- graph mean pool ----------------
__global__ void pool_kernel(const float* __restrict__ h3sum, const float* __restrict__ invdeg,
                            const int* __restrict__ batch, float* __restrict__ gsum,
                            int* __restrict__ gcnt) {
    int c = threadIdx.x;  // 256
    for (int n = blockIdx.x; n < NN; n += gridDim.x) {
        float v = h3sum[(size_t)n * 256 + c] * invdeg[n];
        int g = batch[n];
        atomicAdd(&gsum[(size_t)g * 256 + c], v);
        if (c == 0) atomicAdd(&gcnt[g], 1);
    }
}

// ---------------- final graph MLP ----------------
__global__ void mlp_kernel(const float* __restrict__ gsum, const int* __restrict__ gcnt,
                           const float* __restrict__ W1, const float* __restrict__ b1,
                           const float* __restrict__ W2, const float* __restrict__ b2,
                           float* __restrict__ out) {
    int g = blockIdx.x;
    int t = threadIdx.x;  // 256
    __shared__ float grow[256];
    __shared__ float r0s[256], r1s[256];
    int cnt = gcnt[g];
    float inv = 1.0f / (float)(cnt > 0 ? cnt : 1);
    grow[t] = gsum[(size_t)g * 256 + t] * inv;
    __syncthreads();
    float acc = b1[t];
    for (int k = 0; k < 256; k++) acc = fmaf(grow[k], W1[k * 256 + t], acc);
    float h = fmaxf(acc, 0.f);
    r0s[t] = h * W2[t * 2 + 0];
    r1s[t] = h * W2[t * 2 + 1];
    __syncthreads();
    for (int s = 128; s > 0; s >>= 1) {
        if (t < s) { r0s[t] += r0s[t + s]; r1s[t] += r1s[t + s]; }
        __syncthreads();
    }
    if (t == 0) {
        out[g * 2 + 0] = r0s[0] + b2[0];
        out[g * 2 + 1] = r1s[0] + b2[1];
    }
}

extern "C" void kernel_launch(void* const* d_in, const int* in_sizes, int n_in,
                              void* d_out, int out_size, void* d_ws, size_t ws_size,
                              hipStream_t stream) {
    const float* x      = (const float*)d_in[0];
    const int*   ei     = (const int*)d_in[1];
    const int*   src    = ei;
    const int*   dstp   = ei + NE;
    const int*   batch  = (const int*)d_in[2];
    const float* c1_w1  = (const float*)d_in[3];
    const float* c1_b1  = (const float*)d_in[4];
    const float* c1_gn1 = (const float*)d_in[5];
    const float* c1_w2  = (const float*)d_in[6];
    const float* c1_b2  = (const float*)d_in[7];
    const float* c1_gn2 = (const float*)d_in[8];
    const float* c1_w3  = (const float*)d_in[9];
    const float* c1_b3  = (const float*)d_in[10];
    const float* c1_gn3 = (const float*)d_in[11];
    const float* c2_w1  = (const float*)d_in[12];
    const float* c2_b1  = (const float*)d_in[13];
    const float* c2_gn1 = (const float*)d_in[14];
    const float* c2_w2  = (const float*)d_in[15];
    const float* c2_b2  = (const float*)d_in[16];
    const float* c2_gn2 = (const float*)d_in[17];
    const float* c3_w1  = (const float*)d_in[18];
    const float* c3_b1  = (const float*)d_in[19];
    const float* c3_gn1 = (const float*)d_in[20];
    const float* lin_w1 = (const float*)d_in[21];
    const float* lin_b1 = (const float*)d_in[22];
    const float* lin_w2 = (const float*)d_in[23];
    const float* lin_b2 = (const float*)d_in[24];
    float* out = (float*)d_out;

    // ======== workspace: ping-pong regions RA / RB (102.4 MB each) + tail ========
    //   RA: RQ1[NN,256]bf16 -> Y1c[NE,128]bf16 -> RQ2[NN,512]bf16 -> RQ3[NN,512]bf16
    //   RB: Y1b[NE,128]bf16 -> h1sum[NN,128]f32 -> h2sum[NN,256]f32 -> h3sum[NN,256]f32
    // conv2-L2 edge tensor never materialized (stats pass + recompute-scatter pass).
    constexpr size_t REG_BYTES = (size_t)NE * 128 * 2;  // 102,400,000
    constexpr size_t NEED = 2 * REG_BYTES + 4 * 1024 * 1024;

    if (ws_size < NEED) {
        diag_kernel<<<(out_size + 255) / 256, 256, 0, stream>>>(
            out, out_size, (float)(ws_size >> 20));
        return;
    }

    char* base = (char*)d_ws;
    unsigned short* RA = (unsigned short*)base;
    unsigned short* RB = (unsigned short*)(base + REG_BYTES);
    float* h1sum = (float*)RB;
    float* h2sum = (float*)RB;
    float* h3sum = (float*)RB;
    char* p = base + 2 * REG_BYTES;
    auto alloc = [&](size_t bytes) -> void* {
        void* r = (void*)p;
        p += (bytes + 255) & ~(size_t)255;
        return r;
    };
    unsigned short* c1w2t = (unsigned short*)alloc((size_t)128 * 128 * 2);
    unsigned short* c1w3t = (unsigned short*)alloc((size_t)128 * 128 * 2);
    unsigned short* c2w2t = (unsigned short*)alloc((size_t)256 * 256 * 2);
    unsigned short* Wpt   = (unsigned short*)alloc((size_t)512 * 256 * 2);
    int*   deg    = (int*)alloc((size_t)NN * 4);
    float* invdeg = (float*)alloc((size_t)NN * 4);
    float* ssum   = (float*)alloc(256 * 4);
    float* ssq    = (float*)alloc(256 * 4);
    float* al0    = (float*)alloc(256 * 4);
    float* be0    = (float*)alloc(256 * 4);
    float* al1    = (float*)alloc(256 * 4);
    float* be1    = (float*)alloc(256 * 4);
    float* gsum   = (float*)alloc((size_t)NG * 256 * 4);
    int*   gcnt   = (int*)alloc((size_t)NG * 4);

    const float invE = 1.0f / (float)NE;
    const int MT_E = NE / 64;             // 6250 edge row-tiles
    const int MT_N = (NN + 63) / 64;      // 1563 node row-tiles

    hipMemsetAsync(deg, 0, (size_t)NN * 4, stream);
    hipMemsetAsync(gsum, 0, (size_t)NG * 256 * 4, stream);
    hipMemsetAsync(gcnt, 0, (size_t)NG * 4, stream);

    deg_kernel<<<(NE + 255) / 256, 256, 0, stream>>>(dstp, deg);
    invdeg_kernel<<<(NN + 255) / 256, 256, 0, stream>>>(deg, invdeg);

    // weight prep (bf16, transposed [N][K])
    wtrans_kernel<<<(128 * 128 + 255) / 256, 256, 0, stream>>>(c1_w2, c1w2t, 128, 128);
    wtrans_kernel<<<(128 * 128 + 255) / 256, 256, 0, stream>>>(c1_w3, c1w3t, 128, 128);
    wtrans_kernel<<<(256 * 256 + 255) / 256, 256, 0, stream>>>(c2_w2, c2w2t, 256, 256);

    // ================= conv1 =================
    conv1_node_kernel<<<2048, 256, 0, stream>>>(x, c1_w1, RA);  // RQ1 -> RA
    hipMemsetAsync(ssum, 0, 256 * 4, stream);
    hipMemsetAsync(ssq, 0, 256 * 4, stream);
    gstats_kernel<128><<<2048, 256, 0, stream>>>(RA, src, dstp, c1_b1, ssum, ssq);
    finalize_kernel<<<1, 256, 0, stream>>>(ssum, ssq, c1_gn1, 128, invE, al0, be0);

    hipMemsetAsync(ssum, 0, 256 * 4, stream);
    hipMemsetAsync(ssq, 0, 256 * 4, stream);
    // L2: Y1b(RB) = relu(norm(gather(RQ1@RA))) @ c1_w2 + b2, +stats
    mgemm_kernel<128, true, true, false, true, true, false, false>
        <<<dim3(1, MT_E), 256, 0, stream>>>(RA, src, dstp, c1_b1, c1w2t, al0, be0,
                                            nullptr, c1_b2, RB, NE, 128, 128,
                                            ssum, ssq, nullptr, nullptr, nullptr);
    finalize_kernel<<<1, 256, 0, stream>>>(ssum, ssq, c1_gn2, 128, invE, al0, be0);

    hipMemsetAsync(ssum, 0, 256 * 4, stream);
    hipMemsetAsync(ssq, 0, 256 * 4, stream);
    // L3: Y1c(RA) = relu(norm(Y1b@RB)) @ c1_w3 + b3, +stats
    mgemm_kernel<128, false, true, false, true, true, false, false>
        <<<dim3(1, MT_E), 256, 0, stream>>>(RB, nullptr, nullptr, nullptr, c1w3t, al0, be0,
                                            nullptr, c1_b3, RA, NE, 128, 128,
                                            ssum, ssq, nullptr, nullptr, nullptr);
    finalize_kernel<<<1, 256, 0, stream>>>(ssum, ssq, c1_gn3, 128, invE, al0, be0);

    hipMemsetAsync(h1sum, 0, (size_t)NN * 128 * 4, stream);  // RB; Y1b dead
    aggregate_kernel<128><<<2048, 256, 0, stream>>>(RA, dstp, al0, be0, h1sum);

    // ================= conv2 =================
    wprime_t_kernel<<<(512 * 128 + 255) / 256, 256, 0, stream>>>(c2_w1, Wpt, 128, 256);
    // node GEMM: RQ2(RA) = (h1sum@RB * invdeg) @ Wp  [Y1c dead after aggregate1]
    mgemm_kernel<256, false, false, true, false, true, false, true>
        <<<dim3(2, MT_N), 256, 0, stream>>>(h1sum, nullptr, nullptr, nullptr, Wpt,
                                            nullptr, nullptr, invdeg, nullptr, RA,
                                            NN, 128, 512, nullptr, nullptr,
                                            nullptr, nullptr, nullptr);
    hipMemsetAsync(ssum, 0, 256 * 4, stream);
    hipMemsetAsync(ssq, 0, 256 * 4, stream);
    gstats_kernel<256><<<2048, 256, 0, stream>>>(RA, src, dstp, c2_b1, ssum, ssq);
    finalize_kernel<<<1, 256, 0, stream>>>(ssum, ssq, c2_gn1, 256, invE, al0, be0);

    hipMemsetAsync(ssum, 0, 256 * 4, stream);
    hipMemsetAsync(ssq, 0, 256 * 4, stream);
    // pass A (stats only): stats of relu(norm(gather(RQ2))) @ c2_w2 + b2
    mgemm_kernel<256, true, true, false, true, false, false, false>
        <<<dim3(1, MT_E), 256, 0, stream>>>(RA, src, dstp, c2_b1, c2w2t, al0, be0,
                                            nullptr, c2_b2, nullptr, NE, 256, 256,
                                            ssum, ssq, nullptr, nullptr, nullptr);
    finalize_kernel<<<1, 256, 0, stream>>>(ssum, ssq, c2_gn2, 256, invE, al1, be1);

    hipMemsetAsync(h2sum, 0, (size_t)NN * 256 * 4, stream);  // RB; h1sum dead after node GEMM
    // pass B (recompute + fused norm/relu/scatter)
    mgemm_kernel<256, true, true, false, false, false, true, false>
        <<<dim3(1, MT_E), 256, 0, stream>>>(RA, src, dstp, c2_b1, c2w2t, al0, be0,
                                            nullptr, c2_b2, nullptr, NE, 256, 256,
                                            nullptr, nullptr, al1, be1, h2sum);

    // ================= conv3 =================
    wprime_t_kernel<<<(512 * 256 + 255) / 256, 256, 0, stream>>>(c3_w1, Wpt, 256, 256);
    // node GEMM: RQ3(RA) = (h2sum@RB * invdeg) @ Wp  [RQ2 dead after pass B]
    mgemm_kernel<256, false, false, true, false, true, false, true>
        <<<dim3(2, MT_N), 256, 0, stream>>>(h2sum, nullptr, nullptr, nullptr, Wpt,
                                            nullptr, nullptr, invdeg, nullptr, RA,
                                            NN, 256, 512, nullptr, nullptr,
                                            nullptr, nullptr, nullptr);
    hipMemsetAsync(ssum, 0, 256 * 4, stream);
    hipMemsetAsync(ssq, 0, 256 * 4, stream);
    gstats_kernel<256><<<2048, 256, 0, stream>>>(RA, src, dstp, c3_b1, ssum, ssq);
    finalize_kernel<<<1, 256, 0, stream>>>(ssum, ssq, c3_gn1, 256, invE, al0, be0);

    hipMemsetAsync(h3sum, 0, (size_t)NN * 256 * 4, stream);  // RB; h2sum dead after node GEMM
    aggregate_fg_kernel<<<2048, 256, 0, stream>>>(RA, src, dstp, c3_b1, al0, be0, h3sum);

    // ================= pool + MLP =================
    pool_kernel<<<2048, 256, 0, stream>>>(h3sum, invdeg, batch, gsum, gcnt);
    mlp_kernel<<<NG, 256, 0, stream>>>(gsum, gcnt, lin_w1, lin_b1, lin_w2, lin_b2, out);
}